// Round 8
// baseline (158.347 us; speedup 1.0000x reference)
//
#include <hip/hip_runtime.h>
#include <math.h>

#define TLEN 4096
#define BD   1024
#define HDIM 64
#define NB   4

typedef __attribute__((ext_vector_type(8))) short bf16x8;
typedef __attribute__((ext_vector_type(4))) float f32x4;

typedef const __attribute__((address_space(1))) unsigned char* gp_t;
typedef __attribute__((address_space(3))) unsigned char* lp_t;

// async global->LDS, 16 B per lane; LDS dest must be wave-uniform base + lane*16
__device__ __forceinline__ void async_cp16(const void* g, void* l) {
    __builtin_amdgcn_global_load_lds((gp_t)g, (lp_t)l, 16, 0, 0);
}

__device__ __forceinline__ unsigned short f2bf(float f) {
    union { float f; unsigned u; } v; v.f = f;
    unsigned r = v.u + 0x7FFF + ((v.u >> 16) & 1);   // RNE
    return (unsigned short)(r >> 16);
}

__device__ __forceinline__ bf16x8 cvt8(const float4 a, const float4 b) {
    bf16x8 r;
    r[0] = (short)f2bf(a.x); r[1] = (short)f2bf(a.y);
    r[2] = (short)f2bf(a.z); r[3] = (short)f2bf(a.w);
    r[4] = (short)f2bf(b.x); r[5] = (short)f2bf(b.y);
    r[6] = (short)f2bf(b.z); r[7] = (short)f2bf(b.w);
    return r;
}

// ---------------------------------------------------------------------------
// Kernel 0: weights fp32 -> bf16, wbf[192][1024]
// ---------------------------------------------------------------------------
__global__ __launch_bounds__(256) void wconv_kernel(
    const float* __restrict__ wq, const float* __restrict__ wk,
    const float* __restrict__ wv, unsigned short* __restrict__ wbf)
{
    const int r = blockIdx.x;
    const float* src = (r < 64) ? wq : (r < 128) ? wk : wv;
    const int rr = r & 63;
    const int c  = threadIdx.x * 4;
    float4 a = *(const float4*)&src[(size_t)rr * BD + c];
    uint2 o;
    o.x = (unsigned)f2bf(a.x) | ((unsigned)f2bf(a.y) << 16);
    o.y = (unsigned)f2bf(a.z) | ((unsigned)f2bf(a.w) << 16);
    *(uint2*)&wbf[(size_t)r * BD + c] = o;
}

// ---------------------------------------------------------------------------
// Kernel 1: QKV projection. 512 blocks x 4 waves, 32 rows/block, BK=64.
// ALL staging is async global_load_lds issued 1 iter ahead: W as bf16,
// x as RAW FP32 (removes the R7 global->reg->cvt->ds_write round trip whose
// vmcnt wait was the per-iteration stall). fp32->bf16 happens in the A-frag
// read path (2 ds_read_b128 + cvt). Chunk-level XOR swizzle on the GLOBAL
// address (LDS dest must be lane-linear) keeps reads <=2-way bank aliasing.
// Q written PRE-SCALED by 0.125*log2(e).
// ---------------------------------------------------------------------------
__global__ __launch_bounds__(256, 2) void qkv_kernel(
    const float* __restrict__ x,
    const unsigned short* __restrict__ wbf,
    unsigned short* __restrict__ Qb,
    unsigned short* __restrict__ Kb,
    unsigned short* __restrict__ Vt)
{
    const int r0   = blockIdx.x * 32;
    const int tid  = threadIdx.x;
    const int lane = tid & 63;
    const int w    = tid >> 6;
    const int g    = lane >> 4;
    const int c    = lane & 15;

    __shared__ __align__(16) unsigned short wsh[2][192 * 64];  // 24 KB each
    __shared__ __align__(16) float          xf[2][32 * 64];    // 8 KB each (fp32!)
    __shared__ __align__(16) unsigned short vtr[64][40];       // V transpose

    f32x4 acc[3][2];
    #pragma unroll
    for (int t = 0; t < 3; ++t)
        #pragma unroll
        for (int rg = 0; rg < 2; ++rg) acc[t][rg] = (f32x4){0.f, 0.f, 0.f, 0.f};

    // W: 192 rows x 64 bf16 per iter; lds chunk L holds global 16B-chunk
    // (L&7)^(row&7) of its row (swizzle on global side).
    #define STAGE_W(buf, k0s)                                                   \
        {                                                                       \
            _Pragma("unroll")                                                   \
            for (int ii = 0; ii < 6; ++ii) {                                    \
                const int L   = ii * 256 + tid;                                 \
                const int row = L >> 3;                                         \
                const int jl  = (L & 7) ^ (row & 7);                            \
                async_cp16(&wbf[(size_t)row * BD + (k0s) + jl * 8],             \
                           &wsh[buf][L * 8]);                                   \
            }                                                                   \
        }
    // x: 32 rows x 64 fp32 per iter = 16 chunks/row; lds chunk ch holds
    // global chunk ch^(row&15).
    #define STAGE_X(buf, k0s)                                                   \
        {                                                                       \
            _Pragma("unroll")                                                   \
            for (int ii = 0; ii < 2; ++ii) {                                    \
                const int L   = ii * 256 + tid;                                 \
                const int row = L >> 4;                                         \
                const int gch = (L & 15) ^ (row & 15);                          \
                async_cp16(&x[(size_t)(r0 + row) * BD + (k0s) + gch * 4],       \
                           &xf[buf][L * 4]);                                    \
            }                                                                   \
        }

    STAGE_W(0, 0)
    STAGE_X(0, 0)

    for (int it = 0; it < 16; ++it) {
        const int cb = it & 1;
        __syncthreads();   // buf[cb] staged (dma issued a full iter ago)

        if (it < 15) {
            STAGE_W(cb ^ 1, (it + 1) * 64)
            STAGE_X(cb ^ 1, (it + 1) * 64)
        }

        #pragma unroll
        for (int h = 0; h < 2; ++h) {
            const int oct = h * 4 + g;             // logical k-octet (8 elems)
            bf16x8 aX[2], bW[3];
            #pragma unroll
            for (int rg = 0; rg < 2; ++rg) {
                const int row = rg * 16 + c;       // row & 15 == c
                const float4 a0 = *(const float4*)
                    &xf[cb][row * 64 + ((2 * oct) ^ c) * 4];
                const float4 a1 = *(const float4*)
                    &xf[cb][row * 64 + ((2 * oct + 1) ^ c) * 4];
                aX[rg] = cvt8(a0, a1);
            }
            const int slot = (oct ^ (c & 7)) * 8;
            #pragma unroll
            for (int t = 0; t < 3; ++t)
                bW[t] = *(const bf16x8*)&wsh[cb][((w * 3 + t) * 16 + c) * 64 + slot];
            #pragma unroll
            for (int t = 0; t < 3; ++t)
                #pragma unroll
                for (int rg = 0; rg < 2; ++rg)
                    acc[t][rg] = __builtin_amdgcn_mfma_f32_16x16x32_bf16(
                        aX[rg], bW[t], acc[t][rg], 0, 0, 0);
        }
    }

    // ---- epilogue.  C/D frag: row = rg*16 + g*4 + i, col = c (tile m)
    const float qscale = 0.18033688f;   // 0.125 * log2(e)
    const int   bb     = r0 / TLEN;
    const int   trow   = r0 % TLEN;
    #pragma unroll
    for (int t = 0; t < 3; ++t) {
        const int m = w * 3 + t;
        #pragma unroll
        for (int rg = 0; rg < 2; ++rg)
            #pragma unroll
            for (int i = 0; i < 4; ++i) {
                const int row = rg * 16 + g * 4 + i;
                if (m < 4)
                    Qb[(size_t)(r0 + row) * HDIM + m * 16 + c]
                        = f2bf(acc[t][rg][i] * qscale);
                else if (m < 8)
                    Kb[(size_t)(r0 + row) * HDIM + (m - 4) * 16 + c]
                        = f2bf(acc[t][rg][i]);
                else
                    vtr[(m - 8) * 16 + c][row] = f2bf(acc[t][rg][i]);
            }
    }
    __syncthreads();
    {
        const int d    = tid >> 2;
        const int part = tid & 3;
        uint4 v0 = *(const uint4*)&vtr[d][part * 8];
        unsigned short* dst = Vt + (size_t)bb * HDIM * TLEN + (size_t)d * TLEN
                            + trow + part * 8;
        *(uint4*)&dst[0] = v0;
    }
    #undef STAGE_W
    #undef STAGE_X
}

// ---------------------------------------------------------------------------
// Kernel 2: flash attention (unchanged from R7). 256-thr blocks, 4 waves x
// 32 q-rows = 128q-block. S computed TRANSPOSED so P is written as packed 8B
// stores into pp[q][key] (the PV A-operand layout). Max-free softmax
// (Q pre-scaled), exp2-only, scalar per-lane l with deferred reductions.
// ---------------------------------------------------------------------------
template <int KEYS>
__global__ __launch_bounds__(256, 2) void attn_kernel(
    const unsigned short* __restrict__ Qb,
    const unsigned short* __restrict__ Kb,
    const unsigned short* __restrict__ Vt,
    float* __restrict__ O1, float* __restrict__ Ml, float* __restrict__ out)
{
    const int b     = blockIdx.y;
    const int q0    = blockIdx.x * 128;
    const int split = blockIdx.z;
    const int sbase = split * KEYS;

    const unsigned short* Qp = Qb + (size_t)b * TLEN * HDIM;
    const unsigned short* Kp = Kb + (size_t)b * TLEN * HDIM + (size_t)sbase * HDIM;
    const unsigned short* Vp = Vt + (size_t)b * HDIM * TLEN + sbase;

    const int tid  = threadIdx.x;
    const int lane = tid & 63;
    const int w    = tid >> 6;
    const int g    = lane >> 4;
    const int c    = lane & 15;

    __shared__ __align__(16) unsigned short ks[2][4096];   // swizzled [key][d]
    __shared__ __align__(16) unsigned short vs[2][4096];   // swizzled [d][key]
    __shared__ __align__(16) unsigned short pp[128][72];   // [q local][key]

    bf16x8 qB[2][2];
    #pragma unroll
    for (int h = 0; h < 2; ++h)
        #pragma unroll
        for (int kk = 0; kk < 2; ++kk)
            qB[h][kk] = *(const bf16x8*)
                &Qp[(size_t)(q0 + w * 32 + h * 16 + c) * HDIM + kk * 32 + g * 8];

    float lsum[2] = {0.f, 0.f};
    f32x4 oacc[2][4];
    #pragma unroll
    for (int h = 0; h < 2; ++h)
        #pragma unroll
        for (int t = 0; t < 4; ++t) oacc[h][t] = (f32x4){0.f, 0.f, 0.f, 0.f};

    const int nt = KEYS / 64;

    #pragma unroll
    for (int ii = 0; ii < 2; ++ii) {
        const int L   = ii * 256 + tid;
        const int row = L >> 3;
        const int jl  = (L & 7) ^ (row & 7);
        async_cp16(&Kp[(size_t)row * HDIM + jl * 8], &ks[0][L * 8]);
        async_cp16(&Vp[(size_t)row * TLEN + jl * 8], &vs[0][L * 8]);
    }

    for (int it = 0; it < nt; ++it) {
        const int cb = it & 1;
        __syncthreads();

        if (it + 1 < nt) {
            const int s0  = (it + 1) * 64;
            const int nb2 = cb ^ 1;
            #pragma unroll
            for (int ii = 0; ii < 2; ++ii) {
                const int L   = ii * 256 + tid;
                const int row = L >> 3;
                const int jl  = (L & 7) ^ (row & 7);
                async_cp16(&Kp[(size_t)(s0 + row) * HDIM + jl * 8], &ks[nb2][L * 8]);
                async_cp16(&Vp[(size_t)row * TLEN + s0 + jl * 8],   &vs[nb2][L * 8]);
            }
        }

        // ---- S^T = K Q^T : D[m=key 16t+g*4+i][n=q=c]
        f32x4 sacc[2][4];
        #pragma unroll
        for (int h = 0; h < 2; ++h)
            #pragma unroll
            for (int t = 0; t < 4; ++t) sacc[h][t] = (f32x4){0.f, 0.f, 0.f, 0.f};
        #pragma unroll
        for (int t = 0; t < 4; ++t) {
            const int r  = 16 * t + c;
            const int j0 = g ^ (r & 7);
            bf16x8 kA0 = *(const bf16x8*)&ks[cb][(r * 8 + j0) * 8];
            bf16x8 kA1 = *(const bf16x8*)&ks[cb][(r * 8 + (j0 ^ 4)) * 8];
            #pragma unroll
            for (int h = 0; h < 2; ++h) {
                sacc[h][t] = __builtin_amdgcn_mfma_f32_16x16x32_bf16(
                    kA0, qB[h][0], sacc[h][t], 0, 0, 0);
                sacc[h][t] = __builtin_amdgcn_mfma_f32_16x16x32_bf16(
                    kA1, qB[h][1], sacc[h][t], 0, 0, 0);
            }
        }

        // ---- max-free softmax on S^T; packed 8B P stores
        #pragma unroll
        for (int h = 0; h < 2; ++h) {
            const int qloc = w * 32 + h * 16 + c;
            #pragma unroll
            for (int t = 0; t < 4; ++t) {
                float p0 = __builtin_amdgcn_exp2f(sacc[h][t][0]);
                float p1 = __builtin_amdgcn_exp2f(sacc[h][t][1]);
                float p2 = __builtin_amdgcn_exp2f(sacc[h][t][2]);
                float p3 = __builtin_amdgcn_exp2f(sacc[h][t][3]);
                unsigned u0 = __float_as_uint(p0) & 0xffff0000u;
                unsigned u1 = __float_as_uint(p1) & 0xffff0000u;
                unsigned u2 = __float_as_uint(p2) & 0xffff0000u;
                unsigned u3 = __float_as_uint(p3) & 0xffff0000u;
                lsum[h] += (__uint_as_float(u0) + __uint_as_float(u1))
                         + (__uint_as_float(u2) + __uint_as_float(u3));
                uint2 pk;
                pk.x = (u0 >> 16) | u1;
                pk.y = (u2 >> 16) | u3;
                *(uint2*)&pp[qloc][16 * t + g * 4] = pk;
            }
        }

        // ---- O += P V
        bf16x8 pA[2][2];
        #pragma unroll
        for (int h = 0; h < 2; ++h) {
            pA[h][0] = *(const bf16x8*)&pp[w * 32 + h * 16 + c][g * 8];
            pA[h][1] = *(const bf16x8*)&pp[w * 32 + h * 16 + c][32 + g * 8];
        }
        #pragma unroll
        for (int t = 0; t < 4; ++t) {
            const int r  = 16 * t + c;
            const int j0 = g ^ (r & 7);
            bf16x8 vB0 = *(const bf16x8*)&vs[cb][(r * 8 + j0) * 8];
            bf16x8 vB1 = *(const bf16x8*)&vs[cb][(r * 8 + (j0 ^ 4)) * 8];
            #pragma unroll
            for (int h = 0; h < 2; ++h) {
                oacc[h][t] = __builtin_amdgcn_mfma_f32_16x16x32_bf16(
                    pA[h][0], vB0, oacc[h][t], 0, 0, 0);
                oacc[h][t] = __builtin_amdgcn_mfma_f32_16x16x32_bf16(
                    pA[h][1], vB1, oacc[h][t], 0, 0, 0);
            }
        }
    }

    #pragma unroll
    for (int h = 0; h < 2; ++h) {
        lsum[h] += __shfl_xor(lsum[h], 16);
        lsum[h] += __shfl_xor(lsum[h], 32);
    }

    #pragma unroll
    for (int h = 0; h < 2; ++h) {
        const size_t orow = (size_t)(b * TLEN + q0 + w * 32 + h * 16 + g * 4);
        if (KEYS == TLEN) {
            #pragma unroll
            for (int i = 0; i < 4; ++i) {
                const float inv = 1.0f / __shfl(lsum[h], g * 4 + i);
                #pragma unroll
                for (int t = 0; t < 4; ++t)
                    out[(orow + i) * HDIM + 16 * t + c] = oacc[h][t][i] * inv;
            }
        } else {
            float* Od = (split == 0)
                ? out : O1 + (size_t)(split - 1) * NB * TLEN * HDIM;
            #pragma unroll
            for (int i = 0; i < 4; ++i)
                #pragma unroll
                for (int t = 0; t < 4; ++t)
                    Od[(orow + i) * HDIM + 16 * t + c] = oacc[h][t][i];
            if (lane < 16)
                Ml[(size_t)(split * NB + b) * TLEN
                   + q0 + w * 32 + h * 16 + lane] = lsum[h];
        }
    }
}

// ---------------------------------------------------------------------------
// Kernel 3: merge 4 splits: out = (O0+O1+O2+O3) / (l0+l1+l2+l3)
// ---------------------------------------------------------------------------
__global__ __launch_bounds__(256) void merge_kernel(
    float* __restrict__ out, const float* __restrict__ O1,
    const float* __restrict__ Ml)
{
    const int idx  = blockIdx.x * 256 + threadIdx.x;
    const int row  = idx >> 4;
    const int col4 = (idx & 15) * 4;
    const int b    = row >> 12;
    const int t    = row & (TLEN - 1);
    float l = 0.f;
    #pragma unroll
    for (int s = 0; s < 4; ++s) l += Ml[(size_t)(s * NB + b) * TLEN + t];
    const float inv = 1.0f / l;
    float4 a = *(const float4*)&out[(size_t)row * HDIM + col4];
    #pragma unroll
    for (int s = 1; s < 4; ++s) {
        float4 p = *(const float4*)
            &O1[(size_t)(s - 1) * NB * TLEN * HDIM + (size_t)row * HDIM + col4];
        a.x += p.x; a.y += p.y; a.z += p.z; a.w += p.w;
    }
    a.x *= inv; a.y *= inv; a.z *= inv; a.w *= inv;
    *(float4*)&out[(size_t)row * HDIM + col4] = a;
}

// ---------------------------------------------------------------------------
extern "C" void kernel_launch(void* const* d_in, const int* in_sizes, int n_in,
                              void* d_out, int out_size, void* d_ws, size_t ws_size,
                              hipStream_t stream)
{
    (void)in_sizes; (void)n_in; (void)out_size;
    const float* x  = (const float*)d_in[0];
    const float* wq = (const float*)d_in[1];
    const float* wk = (const float*)d_in[2];
    const float* wv = (const float*)d_in[3];
    float* out = (float*)d_out;

    unsigned short* wbf = (unsigned short*)d_out;     // parked; consumed by qkv
    unsigned short* Qbf = (unsigned short*)d_ws;
    unsigned short* Kbf = Qbf + (size_t)NB * TLEN * HDIM;
    unsigned short* Vtb = Kbf + (size_t)NB * TLEN * HDIM;
    float* Ml = (float*)((char*)d_ws + (size_t)3 * NB * TLEN * HDIM * 2);
    float* O1 = Ml + (size_t)4 * NB * TLEN;
    const size_t ws_need = (size_t)3 * NB * TLEN * HDIM * 2     // QKV bf16
                         + (size_t)4 * NB * TLEN * 4            // Ml (4 splits)
                         + (size_t)3 * NB * TLEN * HDIM * 4;    // O1..O3
    const bool use_split = ws_size >= ws_need;

    wconv_kernel<<<dim3(192), 256, 0, stream>>>(wq, wk, wv, wbf);
    qkv_kernel<<<dim3(NB * TLEN / 32), 256, 0, stream>>>(x, wbf, Qbf, Kbf, Vtb);

    if (use_split) {
        attn_kernel<TLEN / 4><<<dim3(TLEN / 128, NB, 4), 256, 0, stream>>>(
            Qbf, Kbf, Vtb, O1, Ml, out);
        merge_kernel<<<dim3(NB * TLEN * 16 / 256), 256, 0, stream>>>(out, O1, Ml);
    } else {
        attn_kernel<TLEN><<<dim3(TLEN / 128, NB, 1), 256, 0, stream>>>(
            Qbf, Kbf, Vtb, O1, Ml, out);
    }
}

// Round 9
// 147.391 us; speedup vs baseline: 1.0743x; 1.0743x over previous
//
#include <hip/hip_runtime.h>
#include <math.h>

#define TLEN 4096
#define BD   1024
#define HDIM 64
#define NB   4

typedef __attribute__((ext_vector_type(8))) short bf16x8;
typedef __attribute__((ext_vector_type(4))) float f32x4;

typedef const __attribute__((address_space(1))) unsigned char* gp_t;
typedef __attribute__((address_space(3))) unsigned char* lp_t;

// async global->LDS DMA. NOTE (R8 finding): this path appears capped at
// ~10 B/cyc/CU even for L2-hot data — use ONLY for HBM-bound streams.
__device__ __forceinline__ void async_cp16(const void* g, void* l) {
    __builtin_amdgcn_global_load_lds((gp_t)g, (lp_t)l, 16, 0, 0);
}

__device__ __forceinline__ unsigned short f2bf(float f) {
    union { float f; unsigned u; } v; v.f = f;
    unsigned r = v.u + 0x7FFF + ((v.u >> 16) & 1);   // RNE
    return (unsigned short)(r >> 16);
}

__device__ __forceinline__ bf16x8 cvt8(const float4 a, const float4 b) {
    bf16x8 r;
    r[0] = (short)f2bf(a.x); r[1] = (short)f2bf(a.y);
    r[2] = (short)f2bf(a.z); r[3] = (short)f2bf(a.w);
    r[4] = (short)f2bf(b.x); r[5] = (short)f2bf(b.y);
    r[6] = (short)f2bf(b.z); r[7] = (short)f2bf(b.w);
    return r;
}

// ---------------------------------------------------------------------------
// Kernel 0: weights fp32 -> bf16, wbf[192][1024]
// ---------------------------------------------------------------------------
__global__ __launch_bounds__(256) void wconv_kernel(
    const float* __restrict__ wq, const float* __restrict__ wk,
    const float* __restrict__ wv, unsigned short* __restrict__ wbf)
{
    const int r = blockIdx.x;
    const float* src = (r < 64) ? wq : (r < 128) ? wk : wv;
    const int rr = r & 63;
    const int c  = threadIdx.x * 4;
    float4 a = *(const float4*)&src[(size_t)rr * BD + c];
    uint2 o;
    o.x = (unsigned)f2bf(a.x) | ((unsigned)f2bf(a.y) << 16);
    o.y = (unsigned)f2bf(a.z) | ((unsigned)f2bf(a.w) << 16);
    *(uint2*)&wbf[(size_t)r * BD + c] = o;
}

// ---------------------------------------------------------------------------
// Kernel 1: QKV projection. 512 blocks x 4 waves, 32 rows/block, BK=64.
// R9: W staged via buffer_load->VGPR->ds_write (L2 path, ~56 B/cyc/CU) —
// OFF the ~10 B/cyc/CU global_load_lds DMA path that capped R6-R8 at 42 µs.
// x (HBM-bound stream) stays on DMA as raw fp32; fp32->bf16 in the A-frag
// read path. LDS layouts identical to R8 (XOR chunk swizzle on global side).
// Q written PRE-SCALED by 0.125*log2(e).
// ---------------------------------------------------------------------------
__global__ __launch_bounds__(256, 2) void qkv_kernel(
    const float* __restrict__ x,
    const unsigned short* __restrict__ wbf,
    unsigned short* __restrict__ Qb,
    unsigned short* __restrict__ Kb,
    unsigned short* __restrict__ Vt)
{
    const int r0   = blockIdx.x * 32;
    const int tid  = threadIdx.x;
    const int lane = tid & 63;
    const int w    = tid >> 6;
    const int g    = lane >> 4;
    const int c    = lane & 15;

    __shared__ __align__(16) unsigned short wsh[2][192 * 64];  // 24 KB each
    __shared__ __align__(16) float          xf[2][32 * 64];    // 8 KB each (fp32)
    __shared__ __align__(16) unsigned short vtr[64][40];       // V transpose

    f32x4 acc[3][2];
    #pragma unroll
    for (int t = 0; t < 3; ++t)
        #pragma unroll
        for (int rg = 0; rg < 2; ++rg) acc[t][rg] = (f32x4){0.f, 0.f, 0.f, 0.f};

    uint4 wreg[6];

    // W: manual loads (L2 path). lds chunk L holds global chunk (L&7)^(row&7).
    #define LOAD_W(k0s)                                                         \
        {                                                                       \
            _Pragma("unroll")                                                   \
            for (int ii = 0; ii < 6; ++ii) {                                    \
                const int L   = ii * 256 + tid;                                 \
                const int row = L >> 3;                                         \
                const int jl  = (L & 7) ^ (row & 7);                            \
                wreg[ii] = *(const uint4*)&wbf[(size_t)row * BD + (k0s) + jl * 8]; \
            }                                                                   \
        }
    #define WRITE_W(buf)                                                        \
        {                                                                       \
            _Pragma("unroll")                                                   \
            for (int ii = 0; ii < 6; ++ii) {                                    \
                const int L = ii * 256 + tid;                                   \
                *(uint4*)&wsh[buf][L * 8] = wreg[ii];                           \
            }                                                                   \
        }
    // x: async DMA as fp32; lds chunk ch holds global chunk ch^(row&15).
    #define STAGE_X(buf, k0s)                                                   \
        {                                                                       \
            _Pragma("unroll")                                                   \
            for (int ii = 0; ii < 2; ++ii) {                                    \
                const int L   = ii * 256 + tid;                                 \
                const int row = L >> 4;                                         \
                const int gch = (L & 15) ^ (row & 15);                          \
                async_cp16(&x[(size_t)(r0 + row) * BD + (k0s) + gch * 4],       \
                           &xf[buf][L * 4]);                                    \
            }                                                                   \
        }

    LOAD_W(0)
    STAGE_X(0, 0)
    WRITE_W(0)

    for (int it = 0; it < 16; ++it) {
        const int cb = it & 1;
        __syncthreads();   // buf[cb] staged

        if (it < 15) {
            LOAD_W((it + 1) * 64)        // L2 loads into regs (latency hidden
            STAGE_X(cb ^ 1, (it + 1) * 64)  //  under this iter's compute)
        }

        #pragma unroll
        for (int h = 0; h < 2; ++h) {
            const int oct = h * 4 + g;             // logical k-octet (8 elems)
            bf16x8 aX[2], bW[3];
            #pragma unroll
            for (int rg = 0; rg < 2; ++rg) {
                const int row = rg * 16 + c;       // row & 15 == c
                const float4 a0 = *(const float4*)
                    &xf[cb][row * 64 + ((2 * oct) ^ c) * 4];
                const float4 a1 = *(const float4*)
                    &xf[cb][row * 64 + ((2 * oct + 1) ^ c) * 4];
                aX[rg] = cvt8(a0, a1);
            }
            const int slot = (oct ^ (c & 7)) * 8;
            #pragma unroll
            for (int t = 0; t < 3; ++t)
                bW[t] = *(const bf16x8*)&wsh[cb][((w * 3 + t) * 16 + c) * 64 + slot];
            #pragma unroll
            for (int t = 0; t < 3; ++t)
                #pragma unroll
                for (int rg = 0; rg < 2; ++rg)
                    acc[t][rg] = __builtin_amdgcn_mfma_f32_16x16x32_bf16(
                        aX[rg], bW[t], acc[t][rg], 0, 0, 0);
        }

        if (it < 15) WRITE_W(cb ^ 1)   // ds_write after compute; vmcnt covered
    }

    // ---- epilogue.  C/D frag: row = rg*16 + g*4 + i, col = c (tile m)
    const float qscale = 0.18033688f;   // 0.125 * log2(e)
    const int   bb     = r0 / TLEN;
    const int   trow   = r0 % TLEN;
    #pragma unroll
    for (int t = 0; t < 3; ++t) {
        const int m = w * 3 + t;
        #pragma unroll
        for (int rg = 0; rg < 2; ++rg)
            #pragma unroll
            for (int i = 0; i < 4; ++i) {
                const int row = rg * 16 + g * 4 + i;
                if (m < 4)
                    Qb[(size_t)(r0 + row) * HDIM + m * 16 + c]
                        = f2bf(acc[t][rg][i] * qscale);
                else if (m < 8)
                    Kb[(size_t)(r0 + row) * HDIM + (m - 4) * 16 + c]
                        = f2bf(acc[t][rg][i]);
                else
                    vtr[(m - 8) * 16 + c][row] = f2bf(acc[t][rg][i]);
            }
    }
    __syncthreads();
    {
        const int d    = tid >> 2;
        const int part = tid & 3;
        uint4 v0 = *(const uint4*)&vtr[d][part * 8];
        unsigned short* dst = Vt + (size_t)bb * HDIM * TLEN + (size_t)d * TLEN
                            + trow + part * 8;
        *(uint4*)&dst[0] = v0;
    }
    #undef LOAD_W
    #undef WRITE_W
    #undef STAGE_X
}

// ---------------------------------------------------------------------------
// Kernel 2: flash attention. 256-thr blocks, 4 waves x 32 q-rows = 128q-block.
// R9: K/V staged via buffer_load->VGPR->ds_write (L2 path) instead of the
// capped DMA path. Loads for it+1 issued right after the barrier; ds_writes
// into buf cb^1 placed after the S-MFMAs (vmcnt latency covered; dbuf makes
// mid-iteration writes race-free). S computed TRANSPOSED, packed 8B P
// stores, max-free exp2 softmax (Q pre-scaled), deferred l-reduce.
// ---------------------------------------------------------------------------
template <int KEYS>
__global__ __launch_bounds__(256, 2) void attn_kernel(
    const unsigned short* __restrict__ Qb,
    const unsigned short* __restrict__ Kb,
    const unsigned short* __restrict__ Vt,
    float* __restrict__ O1, float* __restrict__ Ml, float* __restrict__ out)
{
    const int b     = blockIdx.y;
    const int q0    = blockIdx.x * 128;
    const int split = blockIdx.z;
    const int sbase = split * KEYS;

    const unsigned short* Qp = Qb + (size_t)b * TLEN * HDIM;
    const unsigned short* Kp = Kb + (size_t)b * TLEN * HDIM + (size_t)sbase * HDIM;
    const unsigned short* Vp = Vt + (size_t)b * HDIM * TLEN + sbase;

    const int tid  = threadIdx.x;
    const int lane = tid & 63;
    const int w    = tid >> 6;
    const int g    = lane >> 4;
    const int c    = lane & 15;

    __shared__ __align__(16) unsigned short ks[2][4096];   // swizzled [key][d]
    __shared__ __align__(16) unsigned short vs[2][4096];   // swizzled [d][key]
    __shared__ __align__(16) unsigned short pp[128][72];   // [q local][key]

    bf16x8 qB[2][2];
    #pragma unroll
    for (int h = 0; h < 2; ++h)
        #pragma unroll
        for (int kk = 0; kk < 2; ++kk)
            qB[h][kk] = *(const bf16x8*)
                &Qp[(size_t)(q0 + w * 32 + h * 16 + c) * HDIM + kk * 32 + g * 8];

    float lsum[2] = {0.f, 0.f};
    f32x4 oacc[2][4];
    #pragma unroll
    for (int h = 0; h < 2; ++h)
        #pragma unroll
        for (int t = 0; t < 4; ++t) oacc[h][t] = (f32x4){0.f, 0.f, 0.f, 0.f};

    const int nt = KEYS / 64;

    uint4 kreg[2], vreg[2];
    #define LOAD_KV(s0)                                                         \
        {                                                                       \
            _Pragma("unroll")                                                   \
            for (int ii = 0; ii < 2; ++ii) {                                    \
                const int L   = ii * 256 + tid;                                 \
                const int row = L >> 3;                                         \
                const int jl  = (L & 7) ^ (row & 7);                            \
                kreg[ii] = *(const uint4*)&Kp[(size_t)((s0) + row) * HDIM + jl * 8]; \
                vreg[ii] = *(const uint4*)&Vp[(size_t)row * TLEN + (s0) + jl * 8];   \
            }                                                                   \
        }
    #define WRITE_KV(buf)                                                       \
        {                                                                       \
            _Pragma("unroll")                                                   \
            for (int ii = 0; ii < 2; ++ii) {                                    \
                const int L = ii * 256 + tid;                                   \
                *(uint4*)&ks[buf][L * 8] = kreg[ii];                            \
                *(uint4*)&vs[buf][L * 8] = vreg[ii];                            \
            }                                                                   \
        }

    LOAD_KV(0)
    WRITE_KV(0)

    for (int it = 0; it < nt; ++it) {
        const int cb = it & 1;
        __syncthreads();

        if (it + 1 < nt) LOAD_KV((it + 1) * 64)   // L2 loads, land during S

        // ---- S^T = K Q^T : D[m=key 16t+g*4+i][n=q=c]
        f32x4 sacc[2][4];
        #pragma unroll
        for (int h = 0; h < 2; ++h)
            #pragma unroll
            for (int t = 0; t < 4; ++t) sacc[h][t] = (f32x4){0.f, 0.f, 0.f, 0.f};
        #pragma unroll
        for (int t = 0; t < 4; ++t) {
            const int r  = 16 * t + c;
            const int j0 = g ^ (r & 7);
            bf16x8 kA0 = *(const bf16x8*)&ks[cb][(r * 8 + j0) * 8];
            bf16x8 kA1 = *(const bf16x8*)&ks[cb][(r * 8 + (j0 ^ 4)) * 8];
            #pragma unroll
            for (int h = 0; h < 2; ++h) {
                sacc[h][t] = __builtin_amdgcn_mfma_f32_16x16x32_bf16(
                    kA0, qB[h][0], sacc[h][t], 0, 0, 0);
                sacc[h][t] = __builtin_amdgcn_mfma_f32_16x16x32_bf16(
                    kA1, qB[h][1], sacc[h][t], 0, 0, 0);
            }
        }

        if (it + 1 < nt) WRITE_KV(cb ^ 1)   // dbuf: cb^1 not read this iter

        // ---- max-free softmax on S^T; packed 8B P stores
        #pragma unroll
        for (int h = 0; h < 2; ++h) {
            const int qloc = w * 32 + h * 16 + c;
            #pragma unroll
            for (int t = 0; t < 4; ++t) {
                float p0 = __builtin_amdgcn_exp2f(sacc[h][t][0]);
                float p1 = __builtin_amdgcn_exp2f(sacc[h][t][1]);
                float p2 = __builtin_amdgcn_exp2f(sacc[h][t][2]);
                float p3 = __builtin_amdgcn_exp2f(sacc[h][t][3]);
                unsigned u0 = __float_as_uint(p0) & 0xffff0000u;
                unsigned u1 = __float_as_uint(p1) & 0xffff0000u;
                unsigned u2 = __float_as_uint(p2) & 0xffff0000u;
                unsigned u3 = __float_as_uint(p3) & 0xffff0000u;
                lsum[h] += (__uint_as_float(u0) + __uint_as_float(u1))
                         + (__uint_as_float(u2) + __uint_as_float(u3));
                uint2 pk;
                pk.x = (u0 >> 16) | u1;
                pk.y = (u2 >> 16) | u3;
                *(uint2*)&pp[qloc][16 * t + g * 4] = pk;
            }
        }

        // ---- O += P V
        bf16x8 pA[2][2];
        #pragma unroll
        for (int h = 0; h < 2; ++h) {
            pA[h][0] = *(const bf16x8*)&pp[w * 32 + h * 16 + c][g * 8];
            pA[h][1] = *(const bf16x8*)&pp[w * 32 + h * 16 + c][32 + g * 8];
        }
        #pragma unroll
        for (int t = 0; t < 4; ++t) {
            const int r  = 16 * t + c;
            const int j0 = g ^ (r & 7);
            bf16x8 vB0 = *(const bf16x8*)&vs[cb][(r * 8 + j0) * 8];
            bf16x8 vB1 = *(const bf16x8*)&vs[cb][(r * 8 + (j0 ^ 4)) * 8];
            #pragma unroll
            for (int h = 0; h < 2; ++h) {
                oacc[h][t] = __builtin_amdgcn_mfma_f32_16x16x32_bf16(
                    pA[h][0], vB0, oacc[h][t], 0, 0, 0);
                oacc[h][t] = __builtin_amdgcn_mfma_f32_16x16x32_bf16(
                    pA[h][1], vB1, oacc[h][t], 0, 0, 0);
            }
        }
    }
    #undef LOAD_KV
    #undef WRITE_KV

    #pragma unroll
    for (int h = 0; h < 2; ++h) {
        lsum[h] += __shfl_xor(lsum[h], 16);
        lsum[h] += __shfl_xor(lsum[h], 32);
    }

    #pragma unroll
    for (int h = 0; h < 2; ++h) {
        const size_t orow = (size_t)(b * TLEN + q0 + w * 32 + h * 16 + g * 4);
        if (KEYS == TLEN) {
            #pragma unroll
            for (int i = 0; i < 4; ++i) {
                const float inv = 1.0f / __shfl(lsum[h], g * 4 + i);
                #pragma unroll
                for (int t = 0; t < 4; ++t)
                    out[(orow + i) * HDIM + 16 * t + c] = oacc[h][t][i] * inv;
            }
        } else {
            float* Od = (split == 0)
                ? out : O1 + (size_t)(split - 1) * NB * TLEN * HDIM;
            #pragma unroll
            for (int i = 0; i < 4; ++i)
                #pragma unroll
                for (int t = 0; t < 4; ++t)
                    Od[(orow + i) * HDIM + 16 * t + c] = oacc[h][t][i];
            if (lane < 16)
                Ml[(size_t)(split * NB + b) * TLEN
                   + q0 + w * 32 + h * 16 + lane] = lsum[h];
        }
    }
}

// ---------------------------------------------------------------------------
// Kernel 3: merge 4 splits: out = (O0+O1+O2+O3) / (l0+l1+l2+l3)
// ---------------------------------------------------------------------------
__global__ __launch_bounds__(256) void merge_kernel(
    float* __restrict__ out, const float* __restrict__ O1,
    const float* __restrict__ Ml)
{
    const int idx  = blockIdx.x * 256 + threadIdx.x;
    const int row  = idx >> 4;
    const int col4 = (idx & 15) * 4;
    const int b    = row >> 12;
    const int t    = row & (TLEN - 1);
    float l = 0.f;
    #pragma unroll
    for (int s = 0; s < 4; ++s) l += Ml[(size_t)(s * NB + b) * TLEN + t];
    const float inv = 1.0f / l;
    float4 a = *(const float4*)&out[(size_t)row * HDIM + col4];
    #pragma unroll
    for (int s = 1; s < 4; ++s) {
        float4 p = *(const float4*)
            &O1[(size_t)(s - 1) * NB * TLEN * HDIM + (size_t)row * HDIM + col4];
        a.x += p.x; a.y += p.y; a.z += p.z; a.w += p.w;
    }
    a.x *= inv; a.y *= inv; a.z *= inv; a.w *= inv;
    *(float4*)&out[(size_t)row * HDIM + col4] = a;
}

// ---------------------------------------------------------------------------
extern "C" void kernel_launch(void* const* d_in, const int* in_sizes, int n_in,
                              void* d_out, int out_size, void* d_ws, size_t ws_size,
                              hipStream_t stream)
{
    (void)in_sizes; (void)n_in; (void)out_size;
    const float* x  = (const float*)d_in[0];
    const float* wq = (const float*)d_in[1];
    const float* wk = (const float*)d_in[2];
    const float* wv = (const float*)d_in[3];
    float* out = (float*)d_out;

    unsigned short* wbf = (unsigned short*)d_out;     // parked; consumed by qkv
    unsigned short* Qbf = (unsigned short*)d_ws;
    unsigned short* Kbf = Qbf + (size_t)NB * TLEN * HDIM;
    unsigned short* Vtb = Kbf + (size_t)NB * TLEN * HDIM;
    float* Ml = (float*)((char*)d_ws + (size_t)3 * NB * TLEN * HDIM * 2);
    float* O1 = Ml + (size_t)4 * NB * TLEN;
    const size_t ws_need = (size_t)3 * NB * TLEN * HDIM * 2     // QKV bf16
                         + (size_t)4 * NB * TLEN * 4            // Ml (4 splits)
                         + (size_t)3 * NB * TLEN * HDIM * 4;    // O1..O3
    const bool use_split = ws_size >= ws_need;

    wconv_kernel<<<dim3(192), 256, 0, stream>>>(wq, wk, wv, wbf);
    qkv_kernel<<<dim3(NB * TLEN / 32), 256, 0, stream>>>(x, wbf, Qbf, Kbf, Vtb);

    if (use_split) {
        attn_kernel<TLEN / 4><<<dim3(TLEN / 128, NB, 4), 256, 0, stream>>>(
            Qbf, Kbf, Vtb, O1, Ml, out);
        merge_kernel<<<dim3(NB * TLEN * 16 / 256), 256, 0, stream>>>(out, O1, Ml);
    } else {
        attn_kernel<TLEN><<<dim3(TLEN / 128, NB, 1), 256, 0, stream>>>(
            Qbf, Kbf, Vtb, O1, Ml, out);
    }
}